// Round 3
// baseline (153.543 us; speedup 1.0000x reference)
//
#include <hip/hip_runtime.h>
#include <hip/hip_bf16.h>

#define B_TOT  1024
#define IN_DIM 512
#define C_DIM  128
#define HID    128
#define EMB    32
#define BSUP   256             // rows per super-tile
#define NSUP   (B_TOT / BSUP)  // 4
#define BK     64
#define NKT    (IN_DIM / BK)   // 8

using bf16x8 = __attribute__((ext_vector_type(8))) short;
using f32x4  = __attribute__((ext_vector_type(4))) float;

__device__ __forceinline__ unsigned short f2b(float f) {
    union { __hip_bfloat16 h; unsigned short u; } cv;
    cv.h = __float2bfloat16(f);
    return cv.u;
}
__device__ __forceinline__ unsigned int pack2(float a, float b) {
    return (unsigned int)f2b(a) | ((unsigned int)f2b(b) << 16);
}
__device__ __forceinline__ unsigned long long pack4(float a, float b, float c, float d) {
    return (unsigned long long)pack2(a, b) | ((unsigned long long)pack2(c, d) << 32);
}
__device__ __forceinline__ bf16x8 ld16(const unsigned short* p) {
    return *(const bf16x8*)p;   // 16B-aligned by construction
}

// LDS (dynamic, 163840 B exactly):
//  W1T: smem[0 .. 65536) ushorts (128 KB): (h,k) at h*512 + ((kg^(h&7))<<3) + (k&7), kg=k>>3
//  U  : smem[65536 .. 81920) ushorts (32 KB), time-multiplexed:
//    - W2 staging (kernel start): e*128 + h
//    - Xs (K-loop, single buf):   r*64  + ((kg^(r&7))<<3) + (k&7), kg=k>>3, r in [0,256)
//    - Hs (GEMM2, per 128-row half): r*128 + ((kg^(r&7))<<3) + (h&7), kg=h>>3, r in [0,128)

__global__ __launch_bounds__(512, 1) void bank_fused(
    const float* __restrict__ x,
    const float* __restrict__ pW1, const float* __restrict__ pb1,
    const float* __restrict__ pW2, const float* __restrict__ pb2,
    const float* __restrict__ nW1, const float* __restrict__ nb1,
    const float* __restrict__ nW2, const float* __restrict__ nb2,
    float* __restrict__ out)
{
    extern __shared__ unsigned short smem[];
    unsigned short* const W1T = smem;           // 128 KB
    unsigned short* const U   = smem + 65536;   // 32 KB

    // one block per (c, bank); xcd = c>>4 so each output 64B line (16 c's)
    // is produced within one XCD (write merge in L2).
    const int p    = blockIdx.x;
    const int xcd  = p & 7;
    const int rank = p >> 3;              // 0..31
    const int c    = xcd * 16 + (rank & 15);
    const int bank = rank >> 4;

    const float* W1c = (bank ? nW1 : pW1) + (size_t)c * IN_DIM * HID;
    const float* b1c = (bank ? nb1 : pb1) + c * HID;
    const float* W2c = (bank ? nW2 : pW2) + (size_t)c * HID * EMB;
    const float* b2c = (bank ? nb2 : pb2) + c * EMB;
    float* outb = out + (size_t)bank * B_TOT * EMB * C_DIM;

    const int t    = threadIdx.x;
    const int wave = t >> 6;       // 0..7
    const int lane = t & 63;
    const int lr   = lane & 15;
    const int lkg  = lane >> 4;
    const int wm   = wave >> 1;    // 0..3 (64-row stripe)
    const int wn   = wave & 1;     // 0..1 (64-col stripe)

    // ---- stage W2 -> U (flat [e][h]), pull fragments to registers ----
    if (t < 256) {
        int e0 = (t & 7) * 4, h0 = (t >> 3) * 4;
        const float* src = &W2c[(size_t)h0 * EMB + e0];
        f32x4 L0 = *(const f32x4*)(src + 0 * EMB);
        f32x4 L1 = *(const f32x4*)(src + 1 * EMB);
        f32x4 L2 = *(const f32x4*)(src + 2 * EMB);
        f32x4 L3 = *(const f32x4*)(src + 3 * EMB);
#pragma unroll
        for (int j = 0; j < 4; ++j)
            *(unsigned long long*)&U[(e0 + j) * 128 + h0] =
                pack4(L0[j], L1[j], L2[j], L3[j]);
    }
    __syncthreads();
    bf16x8 w2f[2][4];
#pragma unroll
    for (int ei = 0; ei < 2; ++ei)
#pragma unroll
        for (int k2 = 0; k2 < 4; ++k2)
            w2f[ei][k2] = ld16(&U[(ei * 16 + lr) * 128 + k2 * 32 + lkg * 8]);
    float b1v[4];
#pragma unroll
    for (int ni = 0; ni < 4; ++ni) b1v[ni] = b1c[wn * 64 + ni * 16 + lr];
    float b2v[2];
#pragma unroll
    for (int ei = 0; ei < 2; ++ei) b2v[ei] = b2c[ei * 16 + lr];
    __syncthreads();

    // =================== super-tile loop (4 x 256 rows) ===================
    for (int sup = 0; sup < NSUP; ++sup) {
        const int bbase = sup * BSUP;

        f32x4 acc[4][4];
#pragma unroll
        for (int mi = 0; mi < 4; ++mi)
#pragma unroll
            for (int ni = 0; ni < 4; ++ni) acc[mi][ni] = (f32x4){0.f, 0.f, 0.f, 0.f};

        // --- prologue: stage X k-tile 0 (+ W1 chunk 0 on sup 0) ---
        {
#pragma unroll
            for (int i = 0; i < 8; ++i) {
                int f = i * 512 + t;
                int row = f >> 4, colq = (f & 15) * 4;
                f32x4 v = *(const f32x4*)&x[(size_t)(bbase + row) * IN_DIM + colq];
                int kg = colq >> 3, kin = colq & 7;
                *(unsigned long long*)&U[row * 64 + ((kg ^ (row & 7)) << 3) + kin] =
                    pack4(v[0], v[1], v[2], v[3]);
            }
            if (sup == 0) {
                int h0 = (t & 31) * 4;
                int k0 = (t >> 5) * 4;      // 0..60
                const float* src = &W1c[(size_t)k0 * HID + h0];
                f32x4 L0 = *(const f32x4*)(src + 0 * HID);
                f32x4 L1 = *(const f32x4*)(src + 1 * HID);
                f32x4 L2 = *(const f32x4*)(src + 2 * HID);
                f32x4 L3 = *(const f32x4*)(src + 3 * HID);
                int kg = k0 >> 3, kin = k0 & 7;
#pragma unroll
                for (int j = 0; j < 4; ++j) {
                    int h = h0 + j;
                    *(unsigned long long*)&W1T[h * 512 + ((kg ^ (h & 7)) << 3) + kin] =
                        pack4(L0[j], L1[j], L2[j], L3[j]);
                }
            }
        }
        __syncthreads();

        // --- K loop: issue prefetch -> compute -> barrier -> write -> barrier
        for (int kt = 0; kt < NKT; ++kt) {
            const bool pre = (kt < NKT - 1);
            f32x4 xp[8];
            f32x4 wp[4];
            if (pre) {
                int kb = (kt + 1) * BK;
#pragma unroll
                for (int i = 0; i < 8; ++i) {
                    int f = i * 512 + t;
                    int row = f >> 4, colq = (f & 15) * 4;
                    xp[i] = *(const f32x4*)&x[(size_t)(bbase + row) * IN_DIM + kb + colq];
                }
                if (sup == 0) {
                    int h0 = (t & 31) * 4;
                    int k0 = kb + (t >> 5) * 4;
                    const float* src = &W1c[(size_t)k0 * HID + h0];
                    wp[0] = *(const f32x4*)(src + 0 * HID);
                    wp[1] = *(const f32x4*)(src + 1 * HID);
                    wp[2] = *(const f32x4*)(src + 2 * HID);
                    wp[3] = *(const f32x4*)(src + 3 * HID);
                }
            }

            // compute on current Xs / W1T chunk kt
#pragma unroll
            for (int ki = 0; ki < 2; ++ki) {
                bf16x8 af[4], bfr[4];
                int kg  = ki * 4 + lkg;            // 0..7 (X tile)
                int kgW = kt * 8 + kg;             // 0..63 (W1T)
#pragma unroll
                for (int mi = 0; mi < 4; ++mi) {
                    int r = wm * 64 + mi * 16 + lr;
                    af[mi] = ld16(&U[r * 64 + ((kg ^ (r & 7)) << 3)]);
                }
#pragma unroll
                for (int ni = 0; ni < 4; ++ni) {
                    int h = wn * 64 + ni * 16 + lr;
                    bfr[ni] = ld16(&W1T[h * 512 + ((kgW ^ (h & 7)) << 3)]);
                }
#pragma unroll
                for (int mi = 0; mi < 4; ++mi)
#pragma unroll
                    for (int ni = 0; ni < 4; ++ni)
                        acc[mi][ni] = __builtin_amdgcn_mfma_f32_16x16x32_bf16(
                            af[mi], bfr[ni], acc[mi][ni], 0, 0, 0);
            }
            __syncthreads();

            if (pre) {
#pragma unroll
                for (int i = 0; i < 8; ++i) {
                    int f = i * 512 + t;
                    int row = f >> 4, colq = (f & 15) * 4;
                    int kg = colq >> 3, kin = colq & 7;
                    *(unsigned long long*)&U[row * 64 + ((kg ^ (row & 7)) << 3) + kin] =
                        pack4(xp[i][0], xp[i][1], xp[i][2], xp[i][3]);
                }
                if (sup == 0) {
                    int h0 = (t & 31) * 4;
                    int k0 = (kt + 1) * BK + (t >> 5) * 4;
                    int kg = k0 >> 3, kin = k0 & 7;
#pragma unroll
                    for (int j = 0; j < 4; ++j) {
                        int h = h0 + j;
                        *(unsigned long long*)&W1T[h * 512 + ((kg ^ (h & 7)) << 3) + kin] =
                            pack4(wp[0][j], wp[1][j], wp[2][j], wp[3][j]);
                    }
                }
                __syncthreads();
            }
        }

        // --- epilogue1 + GEMM2, per 128-row half over U (Hs) ---
#pragma unroll
        for (int half = 0; half < 2; ++half) {
            if ((wm >> 1) == half) {
#pragma unroll
                for (int mi = 0; mi < 4; ++mi) {
                    int row0 = (wm & 1) * 64 + mi * 16 + lkg * 4;
#pragma unroll
                    for (int ni = 0; ni < 4; ++ni) {
                        int col = wn * 64 + ni * 16 + lr;
                        int kgH = col >> 3, kin = col & 7;
#pragma unroll
                        for (int j = 0; j < 4; ++j) {
                            int r = row0 + j;
                            float v = fmaxf(acc[mi][ni][j] + b1v[ni], 0.f);
                            U[r * 128 + ((kgH ^ (r & 7)) << 3) + kin] = f2b(v);
                        }
                    }
                }
            }
            __syncthreads();

            // GEMM2 on this half: M=128 (16 rows/wave), N=32, K=128
            f32x4 acc2[2];
#pragma unroll
            for (int ei = 0; ei < 2; ++ei) acc2[ei] = (f32x4){0.f, 0.f, 0.f, 0.f};
            const int rb = wave * 16;
#pragma unroll
            for (int k2 = 0; k2 < 4; ++k2) {
                int kg = k2 * 4 + lkg;      // 0..15
                int r  = rb + lr;
                bf16x8 a2 = ld16(&U[r * 128 + ((kg ^ (r & 7)) << 3)]);
#pragma unroll
                for (int ei = 0; ei < 2; ++ei)
                    acc2[ei] = __builtin_amdgcn_mfma_f32_16x16x32_bf16(
                        a2, w2f[ei][k2], acc2[ei], 0, 0, 0);
            }

            // stores: out[b][e][c] fp32 (merges within this XCD's L2)
#pragma unroll
            for (int ei = 0; ei < 2; ++ei) {
                int e = ei * 16 + lr;
#pragma unroll
                for (int j = 0; j < 4; ++j) {
                    int brow = bbase + half * 128 + rb + lkg * 4 + j;
                    outb[((size_t)brow * EMB + e) * C_DIM + c] = acc2[ei][j] + b2v[ei];
                }
            }
            __syncthreads();
        }
    }
}

extern "C" void kernel_launch(void* const* d_in, const int* in_sizes, int n_in,
                              void* d_out, int out_size, void* d_ws, size_t ws_size,
                              hipStream_t stream) {
    const float* x   = (const float*)d_in[0];
    const float* pW1 = (const float*)d_in[1];
    const float* pb1 = (const float*)d_in[2];
    const float* pW2 = (const float*)d_in[3];
    const float* pb2 = (const float*)d_in[4];
    const float* nW1 = (const float*)d_in[5];
    const float* nb1 = (const float*)d_in[6];
    const float* nW2 = (const float*)d_in[7];
    const float* nb2 = (const float*)d_in[8];
    float* out = (float*)d_out;

    (void)hipFuncSetAttribute((const void*)bank_fused,
                              hipFuncAttributeMaxDynamicSharedMemorySize, 163840);
    bank_fused<<<dim3(256), dim3(512), 163840, stream>>>(
        x, pW1, pb1, pW2, pb2, nW1, nb1, nW2, nb2, out);
}

// Round 4
// 98.950 us; speedup vs baseline: 1.5517x; 1.5517x over previous
//
#include <hip/hip_runtime.h>
#include <hip/hip_bf16.h>

#define B_TOT  1024
#define IN_DIM 512
#define C_DIM  128
#define HID    128
#define EMB    32
#define BK     64
#define NKT    (IN_DIM / BK)   // 8

// workspace layout (ushort indices)
#define WS_W1_STRIDE 65536ull                  // per (bank,c) pair: 8 chunks x 8192
#define WS_W2_OFF    16777216ull               // 256 pairs x 4096
#define WS_X_OFF     17825792ull               // [1024][512]
#define WS_NEEDED_B  36700160ull               // bytes

using bf16x8 = __attribute__((ext_vector_type(8))) short;
using f32x4  = __attribute__((ext_vector_type(4))) float;

__device__ __forceinline__ unsigned short f2b(float f) {
    union { __hip_bfloat16 h; unsigned short u; } cv;
    cv.h = __float2bfloat16(f);
    return cv.u;
}
__device__ __forceinline__ unsigned int pack2(float a, float b) {
    return (unsigned int)f2b(a) | ((unsigned int)f2b(b) << 16);
}
__device__ __forceinline__ unsigned long long pack4(float a, float b, float c, float d) {
    return (unsigned long long)pack2(a, b) | ((unsigned long long)pack2(c, d) << 32);
}
__device__ __forceinline__ bf16x8 ld16(const unsigned short* p) {
    return *(const bf16x8*)p;
}
__device__ __forceinline__ void g2l16(const unsigned short* g, unsigned short* l) {
    __builtin_amdgcn_global_load_lds(
        (const __attribute__((address_space(1))) unsigned int*)(g),
        (__attribute__((address_space(3))) unsigned int*)(l), 16, 0, 0);
}

// ============================ prepass ============================
// grid 1024, 256 thr. blk -> pair = blk>>2 (bank*128+c), quarter = blk&3.
// Converts W1 -> bf16 [h][k] per 64-k chunk, row-swizzled (kg ^= h&7) so the
// main kernel can stage with a LINEAR global_load_lds copy. W2 -> bf16 [e][h].
// x -> bf16 [row][k] with the same within-row chunk swizzle (kg ^= row&7).
__global__ __launch_bounds__(256) void prepass(
    const float* __restrict__ x,
    const float* __restrict__ pW1, const float* __restrict__ pW2,
    const float* __restrict__ nW1, const float* __restrict__ nW2,
    unsigned short* __restrict__ ws)
{
    __shared__ unsigned short img[8192];   // 16 KB
    const int blk     = blockIdx.x;
    const int pair    = blk >> 2;          // bank*128 + c
    const int quarter = blk & 3;
    const int bank    = pair >> 7;
    const int c       = pair & 127;
    const int t       = threadIdx.x;

    const float* W1c = (bank ? nW1 : pW1) + (size_t)c * IN_DIM * HID;
    const float* W2c = (bank ? nW2 : pW2) + (size_t)c * HID * EMB;

    // ---- W2 (quarter 0 only): micro-transpose -> img[e*128+h], dump 8 KB
    if (quarter == 0) {
        int e0 = (t & 7) * 4, h0 = (t >> 3) * 4;
        const float* src = &W2c[(size_t)h0 * EMB + e0];
        f32x4 L0 = *(const f32x4*)(src + 0 * EMB);
        f32x4 L1 = *(const f32x4*)(src + 1 * EMB);
        f32x4 L2 = *(const f32x4*)(src + 2 * EMB);
        f32x4 L3 = *(const f32x4*)(src + 3 * EMB);
#pragma unroll
        for (int j = 0; j < 4; ++j)
            *(unsigned long long*)&img[(e0 + j) * 128 + h0] =
                pack4(L0[j], L1[j], L2[j], L3[j]);
        __syncthreads();
        unsigned short* dst = ws + WS_W2_OFF + (size_t)pair * 4096;
        *(bf16x8*)&dst[t * 16]     = *(const bf16x8*)&img[t * 16];
        *(bf16x8*)&dst[t * 16 + 8] = *(const bf16x8*)&img[t * 16 + 8];
        __syncthreads();
    }

    // ---- W1: two 64-k chunks per block ----
#pragma unroll
    for (int q = 0; q < 2; ++q) {
        const int kt = quarter * 2 + q;
        const float* Wk = W1c + (size_t)kt * BK * HID;
#pragma unroll
        for (int g = 0; g < 2; ++g) {
            int s  = g * 256 + t;
            int k0 = (s >> 5) * 4;       // 0..60
            int h0 = (s & 31) * 4;       // 0..124
            const float* src = &Wk[(size_t)k0 * HID + h0];
            f32x4 L0 = *(const f32x4*)(src + 0 * HID);
            f32x4 L1 = *(const f32x4*)(src + 1 * HID);
            f32x4 L2 = *(const f32x4*)(src + 2 * HID);
            f32x4 L3 = *(const f32x4*)(src + 3 * HID);
#pragma unroll
            for (int j = 0; j < 4; ++j) {
                int h = h0 + j;
                img[h * 64 + (((k0 >> 3) ^ (h & 7)) << 3) + (k0 & 7)] = 0; // placeholder overwritten below
                *(unsigned long long*)&img[h * 64 + (((k0 >> 3) ^ (h & 7)) << 3) + (k0 & 7)] =
                    pack4(L0[j], L1[j], L2[j], L3[j]);
            }
        }
        __syncthreads();
        unsigned short* dst = ws + (size_t)pair * WS_W1_STRIDE + (size_t)kt * 8192;
#pragma unroll
        for (int i = 0; i < 4; ++i)
            *(bf16x8*)&dst[t * 32 + i * 8] = *(const bf16x8*)&img[t * 32 + i * 8];
        __syncthreads();
    }

    // ---- x: one row per block, chunk-swizzled within the row ----
    {
        const int row = blk;              // 0..1023
        if (t < 128) {
            int k0  = t * 4;                          // dst col
            int cb  = k0 & ~63;
            int kgl = (k0 >> 3) & 7;
            int ks  = cb + ((kgl ^ (row & 7)) << 3) + (k0 & 7);
            f32x4 v = *(const f32x4*)&x[(size_t)row * IN_DIM + ks];
            *(unsigned long long*)&ws[WS_X_OFF + (size_t)row * IN_DIM + k0] =
                pack4(v[0], v[1], v[2], v[3]);
        }
    }
}

// ============================ main ============================
// 2048 blocks, 256 thr, 64 KB static LDS, 2 blocks/CU.
// smem: X0 @0, X1 @8192, W0 @16384, W1 @24576 (ushort idx); Hs reuses [0,16384).
__global__ __launch_bounds__(256, 2) void bank_main(
    const float* __restrict__ pb1, const float* __restrict__ pb2,
    const float* __restrict__ nb1, const float* __restrict__ nb2,
    const unsigned short* __restrict__ ws,
    float* __restrict__ out)
{
    __shared__ unsigned short smem[32768];

    // mapping: same XCD gets c in [xcd*16, xcd*16+16) x all btiles x banks
    // -> output 64B lines (16 c) merge in that XCD's L2 AND W1[c] re-reads
    //    across btiles are L2 hits.
    const int p     = blockIdx.x;
    const int xcd   = p & 7;
    const int rank  = p >> 3;             // 0..255
    const int c     = xcd * 16 + (rank & 15);
    const int btile = (rank >> 4) & 7;
    const int bank  = rank >> 7;
    const int pair  = bank * 128 + c;
    const int bbase = btile * 128;

    const float* b1c = (bank ? nb1 : pb1) + c * HID;
    const float* b2c = (bank ? nb2 : pb2) + c * EMB;
    float* outb = out + (size_t)bank * B_TOT * EMB * C_DIM;

    const int t    = threadIdx.x;
    const int wave = t >> 6;
    const int lane = t & 63;
    const int lr   = lane & 15;
    const int lkg  = lane >> 4;
    const int wm   = wave >> 1;
    const int wn   = wave & 1;

    // W2 fragments straight from ws (bf16 [e][h])
    const unsigned short* w2base = ws + WS_W2_OFF + (size_t)pair * 4096;
    bf16x8 w2f[2][4];
#pragma unroll
    for (int ei = 0; ei < 2; ++ei)
#pragma unroll
        for (int k2 = 0; k2 < 4; ++k2)
            w2f[ei][k2] = ld16(&w2base[(ei * 16 + lr) * 128 + (k2 * 4 + lkg) * 8]);
    float b1v[4];
#pragma unroll
    for (int ni = 0; ni < 4; ++ni) b1v[ni] = b1c[wn * 64 + ni * 16 + lr];
    float b2v[2];
#pragma unroll
    for (int ei = 0; ei < 2; ++ei) b2v[ei] = b2c[ei * 16 + lr];

    const unsigned short* w1base = ws + (size_t)pair * WS_W1_STRIDE;
    const unsigned short* xbase  = ws + WS_X_OFF + (size_t)bbase * IN_DIM;

    f32x4 acc[4][4];
#pragma unroll
    for (int mi = 0; mi < 4; ++mi)
#pragma unroll
        for (int ni = 0; ni < 4; ++ni) acc[mi][ni] = (f32x4){0.f, 0.f, 0.f, 0.f};

    // stage helpers: 16 KB each = 16 wave-instrs (4 per wave), pure linear copy
#define STAGE_X(kt, sel)                                                        \
    {                                                                           \
        unsigned short* ldst = &smem[(sel) * 8192];                             \
        _Pragma("unroll")                                                       \
        for (int i = 0; i < 4; ++i) {                                           \
            int inst = wave * 4 + i;                                            \
            int e    = inst * 512 + lane * 8;                                   \
            int r    = e >> 6, kp = e & 63;                                     \
            g2l16(&xbase[(size_t)r * IN_DIM + (kt) * BK + kp],                  \
                  &ldst[inst * 512]);                                           \
        }                                                                       \
    }
#define STAGE_W(kt, sel)                                                        \
    {                                                                           \
        unsigned short* ldst = &smem[16384 + (sel) * 8192];                     \
        const unsigned short* src = w1base + (size_t)(kt) * 8192;               \
        _Pragma("unroll")                                                       \
        for (int i = 0; i < 4; ++i) {                                           \
            int inst = wave * 4 + i;                                            \
            g2l16(&src[inst * 512 + lane * 8], &ldst[inst * 512]);              \
        }                                                                       \
    }

    STAGE_X(0, 0);
    STAGE_W(0, 0);
    __syncthreads();

    for (int kt = 0; kt < NKT; ++kt) {
        const int sel = kt & 1;
        if (kt < NKT - 1) {
            STAGE_X(kt + 1, sel ^ 1);
            STAGE_W(kt + 1, sel ^ 1);
        }
        const unsigned short* Xb = &smem[sel * 8192];
        const unsigned short* Wb = &smem[16384 + sel * 8192];
#pragma unroll
        for (int ki = 0; ki < 2; ++ki) {
            int kg = ki * 4 + lkg;
            bf16x8 af[4], bfr[4];
#pragma unroll
            for (int mi = 0; mi < 4; ++mi) {
                int r = wm * 64 + mi * 16 + lr;
                af[mi] = ld16(&Xb[r * 64 + ((kg ^ (r & 7)) << 3)]);
            }
#pragma unroll
            for (int ni = 0; ni < 4; ++ni) {
                int h = wn * 64 + ni * 16 + lr;
                bfr[ni] = ld16(&Wb[h * 64 + ((kg ^ (h & 7)) << 3)]);
            }
#pragma unroll
            for (int mi = 0; mi < 4; ++mi)
#pragma unroll
                for (int ni = 0; ni < 4; ++ni)
                    acc[mi][ni] = __builtin_amdgcn_mfma_f32_16x16x32_bf16(
                        af[mi], bfr[ni], acc[mi][ni], 0, 0, 0);
        }
        __syncthreads();
    }

    // epilogue1: bias+relu -> Hs (swizzled [r][h]) over smem[0..16384)
#pragma unroll
    for (int mi = 0; mi < 4; ++mi) {
        int row0 = wm * 64 + mi * 16 + lkg * 4;
#pragma unroll
        for (int ni = 0; ni < 4; ++ni) {
            int col = wn * 64 + ni * 16 + lr;
            int kgH = col >> 3, kin = col & 7;
#pragma unroll
            for (int j = 0; j < 4; ++j) {
                int r = row0 + j;
                float v = fmaxf(acc[mi][ni][j] + b1v[ni], 0.f);
                smem[r * 128 + ((kgH ^ (r & 7)) << 3) + kin] = f2b(v);
            }
        }
    }
    __syncthreads();

    // GEMM2: M=128, N=32, K=128; each wave 32 rows
    f32x4 acc2[2][2];
#pragma unroll
    for (int m2 = 0; m2 < 2; ++m2)
#pragma unroll
        for (int ei = 0; ei < 2; ++ei) acc2[m2][ei] = (f32x4){0.f, 0.f, 0.f, 0.f};
    const int rb = wave * 32;
#pragma unroll
    for (int k2 = 0; k2 < 4; ++k2) {
        int kg = k2 * 4 + lkg;
        bf16x8 a2[2];
#pragma unroll
        for (int m2 = 0; m2 < 2; ++m2) {
            int r = rb + m2 * 16 + lr;
            a2[m2] = ld16(&smem[r * 128 + ((kg ^ (r & 7)) << 3)]);
        }
#pragma unroll
        for (int m2 = 0; m2 < 2; ++m2)
#pragma unroll
            for (int ei = 0; ei < 2; ++ei)
                acc2[m2][ei] = __builtin_amdgcn_mfma_f32_16x16x32_bf16(
                    a2[m2], w2f[ei][k2], acc2[m2][ei], 0, 0, 0);
    }

#pragma unroll
    for (int m2 = 0; m2 < 2; ++m2) {
#pragma unroll
        for (int ei = 0; ei < 2; ++ei) {
            int e = ei * 16 + lr;
#pragma unroll
            for (int j = 0; j < 4; ++j) {
                int brow = bbase + rb + m2 * 16 + lkg * 4 + j;
                outb[((size_t)brow * EMB + e) * C_DIM + c] = acc2[m2][ei][j] + b2v[ei];
            }
        }
    }
#undef STAGE_X
#undef STAGE_W
}

// ===================== fallback (round-1 kernel, known-good) =====================
#define XS_LD 68
#define W1_LD 68
#define HS_LD 132
#define W2_LD 132
__device__ __forceinline__ bf16x8 load8u(const unsigned short* p) {
    union { unsigned long long q[2]; bf16x8 v; } u;
    u.q[0] = *(const unsigned long long*)(p);
    u.q[1] = *(const unsigned long long*)(p + 4);
    return u.v;
}
__global__ __launch_bounds__(256, 2) void bank_fallback(
    const float* __restrict__ x,
    const float* __restrict__ pW1, const float* __restrict__ pb1,
    const float* __restrict__ pW2, const float* __restrict__ pb2,
    const float* __restrict__ nW1, const float* __restrict__ nb1,
    const float* __restrict__ nW2, const float* __restrict__ nb2,
    float* __restrict__ out)
{
    __shared__ unsigned short Xs [128][XS_LD];
    __shared__ unsigned short W1T[HID][W1_LD];
    __shared__ unsigned short Hs [128][HS_LD];
    __shared__ unsigned short W2T[EMB][W2_LD];
    int p = blockIdx.x;
    int xcd = p & 7, rank = p >> 3;
    int c = xcd * 16 + (rank & 15);
    int btile = (rank >> 4) & 7;
    int bank = rank >> 7;
    int bbase = btile * 128;
    const float* W1c = (bank ? nW1 : pW1) + (size_t)c * IN_DIM * HID;
    const float* b1c = (bank ? nb1 : pb1) + c * HID;
    const float* W2c = (bank ? nW2 : pW2) + (size_t)c * HID * EMB;
    const float* b2c = (bank ? nb2 : pb2) + c * EMB;
    float* outb = out + (size_t)bank * B_TOT * EMB * C_DIM;
    int t = threadIdx.x, wave = t >> 6, lane = t & 63;
    int lr = lane & 15, lkg = lane >> 4, wm = wave >> 1, wn = wave & 1;
    {
        int e0 = (t & 7) * 4, h0 = (t >> 3) * 4;
        f32x4 L0 = *(const f32x4*)&W2c[(h0 + 0) * EMB + e0];
        f32x4 L1 = *(const f32x4*)&W2c[(h0 + 1) * EMB + e0];
        f32x4 L2 = *(const f32x4*)&W2c[(h0 + 2) * EMB + e0];
        f32x4 L3 = *(const f32x4*)&W2c[(h0 + 3) * EMB + e0];
#pragma unroll
        for (int j = 0; j < 4; ++j)
            *(unsigned long long*)&W2T[e0 + j][h0] = pack4(L0[j], L1[j], L2[j], L3[j]);
    }
    float b1v[4];
#pragma unroll
    for (int ni = 0; ni < 4; ++ni) b1v[ni] = b1c[wn * 64 + ni * 16 + lr];
    float b2v[2];
#pragma unroll
    for (int ei = 0; ei < 2; ++ei) b2v[ei] = b2c[ei * 16 + lr];
    f32x4 acc[4][4];
#pragma unroll
    for (int mi = 0; mi < 4; ++mi)
#pragma unroll
        for (int ni = 0; ni < 4; ++ni) acc[mi][ni] = (f32x4){0.f, 0.f, 0.f, 0.f};
    for (int kt = 0; kt < NKT; ++kt) {
        int kb = kt * BK;
#pragma unroll
        for (int w8 = 0; w8 < 8; ++w8) {
            int f = w8 * 256 + t;
            int row = f >> 4, col = (f & 15) * 4;
            f32x4 v = *(const f32x4*)&x[(size_t)(bbase + row) * IN_DIM + kb + col];
            *(unsigned long long*)&Xs[row][col] = pack4(v[0], v[1], v[2], v[3]);
        }
#pragma unroll
        for (int g = 0; g < 2; ++g) {
            int s = g * 256 + t;
            int k0 = (s >> 5) * 4, h0 = (s & 31) * 4;
            const float* src = &W1c[(size_t)(kb + k0) * HID + h0];
            f32x4 L0 = *(const f32x4*)(src + 0 * HID);
            f32x4 L1 = *(const f32x4*)(src + 1 * HID);
            f32x4 L2 = *(const f32x4*)(src + 2 * HID);
            f32x4 L3 = *(const f32x4*)(src + 3 * HID);
#pragma unroll
            for (int j = 0; j < 4; ++j)
                *(unsigned long long*)&W1T[h0 + j][k0] = pack4(L0[j], L1[j], L2[j], L3[j]);
        }
        __syncthreads();
#pragma unroll
        for (int ki = 0; ki < 2; ++ki) {
            int kcol = ki * 32 + lkg * 8;
            bf16x8 af[4], bfr[4];
#pragma unroll
            for (int mi = 0; mi < 4; ++mi) af[mi] = load8u(&Xs[wm * 64 + mi * 16 + lr][kcol]);
#pragma unroll
            for (int ni = 0; ni < 4; ++ni) bfr[ni] = load8u(&W1T[wn * 64 + ni * 16 + lr][kcol]);
#pragma unroll
            for (int mi = 0; mi < 4; ++mi)
#pragma unroll
                for (int ni = 0; ni < 4; ++ni)
                    acc[mi][ni] = __builtin_amdgcn_mfma_f32_16x16x32_bf16(
                        af[mi], bfr[ni], acc[mi][ni], 0, 0, 0);
        }
        __syncthreads();
    }
#pragma unroll
    for (int mi = 0; mi < 4; ++mi) {
        int row = wm * 64 + mi * 16 + lkg * 4;
#pragma unroll
        for (int ni = 0; ni < 4; ++ni) {
            int col = wn * 64 + ni * 16 + lr;
#pragma unroll
            for (int j = 0; j < 4; ++j)
                Hs[row + j][col] = f2b(fmaxf(acc[mi][ni][j] + b1v[ni], 0.f));
        }
    }
    __syncthreads();
    f32x4 acc2[2][2];
#pragma unroll
    for (int m2 = 0; m2 < 2; ++m2)
#pragma unroll
        for (int ei = 0; ei < 2; ++ei) acc2[m2][ei] = (f32x4){0.f, 0.f, 0.f, 0.f};
    int rb = wave * 32;
#pragma unroll
    for (int k2 = 0; k2 < 4; ++k2) {
        int kcol = k2 * 32 + lkg * 8;
        bf16x8 a2[2], b2f[2];
#pragma unroll
        for (int m2 = 0; m2 < 2; ++m2) a2[m2] = load8u(&Hs[rb + m2 * 16 + lr][kcol]);
#pragma unroll
        for (int ei = 0; ei < 2; ++ei) b2f[ei] = load8u(&W2T[ei * 16 + lr][kcol]);
#pragma unroll
        for (int m2 = 0; m2 < 2; ++m2)
#pragma unroll
            for (int ei = 0; ei < 2; ++ei)
                acc2[m2][ei] = __builtin_amdgcn_mfma_f32_16x16x32_bf16(
                    a2[m2], b2f[ei], acc2[m2][ei], 0, 0, 0);
    }
#pragma unroll
    for (int m2 = 0; m2 < 2; ++m2)
#pragma unroll
        for (int ei = 0; ei < 2; ++ei) {
            int e = ei * 16 + lr;
#pragma unroll
            for (int j = 0; j < 4; ++j) {
                int brow = bbase + rb + m2 * 16 + lkg * 4 + j;
                outb[((size_t)brow * EMB + e) * C_DIM + c] = acc2[m2][ei][j] + b2v[ei];
            }
        }
}

extern "C" void kernel_launch(void* const* d_in, const int* in_sizes, int n_in,
                              void* d_out, int out_size, void* d_ws, size_t ws_size,
                              hipStream_t stream) {
    const float* x   = (const float*)d_in[0];
    const float* pW1 = (const float*)d_in[1];
    const float* pb1 = (const float*)d_in[2];
    const float* pW2 = (const float*)d_in[3];
    const float* pb2 = (const float*)d_in[4];
    const float* nW1 = (const float*)d_in[5];
    const float* nb1 = (const float*)d_in[6];
    const float* nW2 = (const float*)d_in[7];
    const float* nb2 = (const float*)d_in[8];
    float* out = (float*)d_out;

    if (ws_size >= WS_NEEDED_B) {
        unsigned short* ws = (unsigned short*)d_ws;
        prepass<<<dim3(1024), dim3(256), 0, stream>>>(x, pW1, pW2, nW1, nW2, ws);
        bank_main<<<dim3(2048), dim3(256), 0, stream>>>(pb1, pb2, nb1, nb2, ws, out);
    } else {
        bank_fallback<<<dim3(2048), dim3(256), 0, stream>>>(
            x, pW1, pb1, pW2, pb2, nW1, nb1, nW2, nb2, out);
    }
}

// Round 5
// 93.441 us; speedup vs baseline: 1.6432x; 1.0590x over previous
//
#include <hip/hip_runtime.h>
#include <hip/hip_bf16.h>

#define B_TOT  1024
#define IN_DIM 512
#define C_DIM  128
#define HID    128
#define EMB    32
#define BK     32
#define NKT    (IN_DIM / BK)   // 16

// workspace layout (ushort indices)
#define WS_W1_STRIDE 65536ull                  // per (bank,c): 16 chunks x 4096
#define WS_W2_OFF    16777216ull               // 256 pairs x 4096
#define WS_X_OFF     17825792ull               // [1024][512]
#define WS_NEEDED_B  36700160ull               // bytes

using bf16x8 = __attribute__((ext_vector_type(8))) short;
using f32x4  = __attribute__((ext_vector_type(4))) float;

__device__ __forceinline__ unsigned short f2b(float f) {
    union { __hip_bfloat16 h; unsigned short u; } cv;
    cv.h = __float2bfloat16(f);
    return cv.u;
}
__device__ __forceinline__ unsigned int pack2(float a, float b) {
    return (unsigned int)f2b(a) | ((unsigned int)f2b(b) << 16);
}
__device__ __forceinline__ unsigned long long pack4(float a, float b, float c, float d) {
    return (unsigned long long)pack2(a, b) | ((unsigned long long)pack2(c, d) << 32);
}
__device__ __forceinline__ bf16x8 ld16(const unsigned short* p) {
    return *(const bf16x8*)p;
}
__device__ __forceinline__ void g2l16(const unsigned short* g, unsigned short* l) {
    __builtin_amdgcn_global_load_lds(
        (const __attribute__((address_space(1))) unsigned int*)(g),
        (__attribute__((address_space(3))) unsigned int*)(l), 16, 0, 0);
}

// Swizzles (involutions, pre-applied in ws so g2l stays linear):
//  32-wide rows (X tiles, W1 chunks): elem (r,k): r*32 + ((((r>>1)&3) ^ (k>>3 & 3))<<3) + (k&7)
//  128-wide rows (Hs):               elem (r,h): r*128 + (((h>>3) ^ (r&7))<<3) + (h&7)

// ============================ prepass ============================
// 1024 blocks x 256 thr. pair = blk>>2, quarter = blk&3; x-row = blk.
__global__ __launch_bounds__(256) void prepass(
    const float* __restrict__ x,
    const float* __restrict__ pW1, const float* __restrict__ pW2,
    const float* __restrict__ nW1, const float* __restrict__ nW2,
    unsigned short* __restrict__ ws)
{
    __shared__ unsigned short img[4096];   // 8 KB
    const int blk     = blockIdx.x;
    const int pair    = blk >> 2;          // bank*128 + c
    const int quarter = blk & 3;
    const int bank    = pair >> 7;
    const int c       = pair & 127;
    const int t       = threadIdx.x;

    const float* W1c = (bank ? nW1 : pW1) + (size_t)c * IN_DIM * HID;
    const float* W2c = (bank ? nW2 : pW2) + (size_t)c * HID * EMB;

    // ---- W2 (quarter 0 only): transpose -> [e][h] flat, bf16 ----
    if (quarter == 0) {
        int e0 = (t & 7) * 4, h0 = (t >> 3) * 4;
        const float* src = &W2c[(size_t)h0 * EMB + e0];
        f32x4 L0 = *(const f32x4*)(src + 0 * EMB);
        f32x4 L1 = *(const f32x4*)(src + 1 * EMB);
        f32x4 L2 = *(const f32x4*)(src + 2 * EMB);
        f32x4 L3 = *(const f32x4*)(src + 3 * EMB);
        unsigned short* dst = ws + WS_W2_OFF + (size_t)pair * 4096;
#pragma unroll
        for (int j = 0; j < 4; ++j)
            *(unsigned long long*)&dst[(e0 + j) * 128 + h0] =
                pack4(L0[j], L1[j], L2[j], L3[j]);
    }

    // ---- W1: four 32-k chunks per block, transposed + swizzled ----
#pragma unroll
    for (int q = 0; q < 4; ++q) {
        const int kt = quarter * 4 + q;
        const float* Wk = W1c + (size_t)kt * BK * HID;
        {
            int k0 = (t >> 5) * 4;       // 0..28
            int h0 = (t & 31) * 4;       // 0..124
            const float* src = &Wk[(size_t)k0 * HID + h0];
            f32x4 L0 = *(const f32x4*)(src + 0 * HID);
            f32x4 L1 = *(const f32x4*)(src + 1 * HID);
            f32x4 L2 = *(const f32x4*)(src + 2 * HID);
            f32x4 L3 = *(const f32x4*)(src + 3 * HID);
#pragma unroll
            for (int j = 0; j < 4; ++j) {
                int h = h0 + j;
                int slot = ((h >> 1) & 3) ^ (k0 >> 3);
                *(unsigned long long*)&img[h * 32 + (slot << 3) + (k0 & 7)] =
                    pack4(L0[j], L1[j], L2[j], L3[j]);
            }
        }
        __syncthreads();
        unsigned short* dst = ws + (size_t)pair * WS_W1_STRIDE + (size_t)kt * 4096;
        *(bf16x8*)&dst[t * 16]     = *(const bf16x8*)&img[t * 16];
        *(bf16x8*)&dst[t * 16 + 8] = *(const bf16x8*)&img[t * 16 + 8];
        __syncthreads();
    }

    // ---- x: one row per block, swizzle pre-applied within 32-k chunks ----
    {
        const int row = blk;              // 0..1023
        if (t < 128) {
            int k0  = t * 4;                          // dst col (mult of 4)
            int cb  = k0 & ~31;
            int kg  = (k0 >> 3) & 3;
            int ks  = cb + (((kg ^ ((row >> 1) & 3))) << 3) + (k0 & 7);
            f32x4 v = *(const f32x4*)&x[(size_t)row * IN_DIM + ks];
            *(unsigned long long*)&ws[WS_X_OFF + (size_t)row * IN_DIM + k0] =
                pack4(v[0], v[1], v[2], v[3]);
        }
    }
}

// ============================ main ============================
// 2048 blocks, 256 thr, 32 KB static LDS -> 4 blocks/CU (16 waves/CU).
// smem (ushort idx): X0 @0, X1 @4096, W0 @8192, W1 @12288; Hs overlays [0,16384).
__global__ __launch_bounds__(256, 4) void bank_main(
    const float* __restrict__ pb1, const float* __restrict__ pb2,
    const float* __restrict__ nb1, const float* __restrict__ nb2,
    const unsigned short* __restrict__ ws,
    float* __restrict__ out)
{
    __shared__ unsigned short smem[16384];

    // same-XCD gets c in [xcd*16, xcd*16+16) x all btiles x banks:
    // output 64B lines (16 c) merge in that XCD's L2, W1[c] re-reads L2-hit.
    const int p     = blockIdx.x;
    const int xcd   = p & 7;
    const int rank  = p >> 3;             // 0..255
    const int c     = xcd * 16 + (rank & 15);
    const int btile = (rank >> 4) & 7;
    const int bank  = rank >> 7;
    const int pair  = bank * 128 + c;
    const int bbase = btile * 128;

    const int t    = threadIdx.x;
    const int wave = t >> 6;
    const int lane = t & 63;
    const int lr   = lane & 15;
    const int lkg  = lane >> 4;   // k-group 0..3 (K=32)
    const int wm   = wave >> 1;
    const int wn   = wave & 1;

    const unsigned short* w1base = ws + (size_t)pair * WS_W1_STRIDE;
    const unsigned short* xbase  = ws + WS_X_OFF + (size_t)bbase * IN_DIM;

    f32x4 acc[4][4];
#pragma unroll
    for (int mi = 0; mi < 4; ++mi)
#pragma unroll
        for (int ni = 0; ni < 4; ++ni) acc[mi][ni] = (f32x4){0.f, 0.f, 0.f, 0.f};

    // stage: 8 KB per tile = 8 wave-instrs (2/wave), pure linear LDS dest
#define STAGE_X(kt, sel)                                                        \
    {                                                                           \
        _Pragma("unroll")                                                       \
        for (int i = 0; i < 2; ++i) {                                           \
            int inst = wave * 2 + i;                                            \
            int row  = inst * 16 + (lane >> 2);                                 \
            g2l16(&xbase[(size_t)row * IN_DIM + (kt) * BK + (lane & 3) * 8],    \
                  &smem[(sel) * 4096 + inst * 512]);                            \
        }                                                                       \
    }
#define STAGE_W(kt, sel)                                                        \
    {                                                                           \
        const unsigned short* src = w1base + (size_t)(kt) * 4096;               \
        _Pragma("unroll")                                                       \
        for (int i = 0; i < 2; ++i) {                                           \
            int inst = wave * 2 + i;                                            \
            g2l16(&src[inst * 512 + lane * 8],                                  \
                  &smem[8192 + (sel) * 4096 + inst * 512]);                     \
        }                                                                       \
    }

    STAGE_X(0, 0);
    STAGE_W(0, 0);
    __syncthreads();

    for (int kt = 0; kt < NKT; ++kt) {
        const int sel = kt & 1;
        if (kt < NKT - 1) {
            STAGE_X(kt + 1, sel ^ 1);
            STAGE_W(kt + 1, sel ^ 1);
        }
        const unsigned short* Xb = &smem[sel * 4096];
        const unsigned short* Wb = &smem[8192 + sel * 4096];
        bf16x8 af[4], bfr[4];
#pragma unroll
        for (int mi = 0; mi < 4; ++mi) {
            int r = wm * 64 + mi * 16 + lr;
            int slot = ((r >> 1) & 3) ^ lkg;
            af[mi] = ld16(&Xb[r * 32 + (slot << 3)]);
        }
#pragma unroll
        for (int ni = 0; ni < 4; ++ni) {
            int h = wn * 64 + ni * 16 + lr;
            int slot = ((h >> 1) & 3) ^ lkg;
            bfr[ni] = ld16(&Wb[h * 32 + (slot << 3)]);
        }
#pragma unroll
        for (int mi = 0; mi < 4; ++mi)
#pragma unroll
            for (int ni = 0; ni < 4; ++ni)
                acc[mi][ni] = __builtin_amdgcn_mfma_f32_16x16x32_bf16(
                    af[mi], bfr[ni], acc[mi][ni], 0, 0, 0);
        __syncthreads();
    }

    // biases loaded only now (keeps K-loop register pressure low)
    const float* b1c = (bank ? nb1 : pb1) + c * HID;
    const float* b2c = (bank ? nb2 : pb2) + c * EMB;
    float b1v[4];
#pragma unroll
    for (int ni = 0; ni < 4; ++ni) b1v[ni] = b1c[wn * 64 + ni * 16 + lr];

    // epilogue1: bias+relu -> Hs (swizzled [r][h]) over smem[0..16384)
#pragma unroll
    for (int mi = 0; mi < 4; ++mi) {
        int row0 = wm * 64 + mi * 16 + lkg * 4;
#pragma unroll
        for (int ni = 0; ni < 4; ++ni) {
            int col = wn * 64 + ni * 16 + lr;
            int kgH = col >> 3, kin = col & 7;
#pragma unroll
            for (int j = 0; j < 4; ++j) {
                int r = row0 + j;
                float v = fmaxf(acc[mi][ni][j] + b1v[ni], 0.f);
                smem[r * 128 + ((kgH ^ (r & 7)) << 3) + kin] = f2b(v);
            }
        }
    }
    __syncthreads();

    // W2 fragments from ws (bf16 [e][h]) — loaded after GEMM1
    const unsigned short* w2base = ws + WS_W2_OFF + (size_t)pair * 4096;
    bf16x8 w2f[2][4];
#pragma unroll
    for (int ei = 0; ei < 2; ++ei)
#pragma unroll
        for (int k2 = 0; k2 < 4; ++k2)
            w2f[ei][k2] = ld16(&w2base[(ei * 16 + lr) * 128 + (k2 * 4 + lkg) * 8]);
    float b2v[2];
#pragma unroll
    for (int ei = 0; ei < 2; ++ei) b2v[ei] = b2c[ei * 16 + lr];

    // GEMM2: M=128, N=32, K=128; each wave 32 rows
    f32x4 acc2[2][2];
#pragma unroll
    for (int m2 = 0; m2 < 2; ++m2)
#pragma unroll
        for (int ei = 0; ei < 2; ++ei) acc2[m2][ei] = (f32x4){0.f, 0.f, 0.f, 0.f};
    const int rb = wave * 32;
#pragma unroll
    for (int k2 = 0; k2 < 4; ++k2) {
        int kg = k2 * 4 + lkg;
        bf16x8 a2[2];
#pragma unroll
        for (int m2 = 0; m2 < 2; ++m2) {
            int r = rb + m2 * 16 + lr;
            a2[m2] = ld16(&smem[r * 128 + ((kg ^ (r & 7)) << 3)]);
        }
#pragma unroll
        for (int m2 = 0; m2 < 2; ++m2)
#pragma unroll
            for (int ei = 0; ei < 2; ++ei)
                acc2[m2][ei] = __builtin_amdgcn_mfma_f32_16x16x32_bf16(
                    a2[m2], w2f[ei][k2], acc2[m2][ei], 0, 0, 0);
    }

    float* outb = out + (size_t)bank * B_TOT * EMB * C_DIM;
#pragma unroll
    for (int m2 = 0; m2 < 2; ++m2) {
#pragma unroll
        for (int ei = 0; ei < 2; ++ei) {
            int e = ei * 16 + lr;
#pragma unroll
            for (int j = 0; j < 4; ++j) {
                int brow = bbase + rb + m2 * 16 + lkg * 4 + j;
                outb[((size_t)brow * EMB + e) * C_DIM + c] = acc2[m2][ei][j] + b2v[ei];
            }
        }
    }
#undef STAGE_X
#undef STAGE_W
}

// ===================== fallback (round-1 kernel, known-good) =====================
#define XS_LD 68
#define W1_LD 68
#define HS_LD 132
#define W2_LD 132
__device__ __forceinline__ bf16x8 load8u(const unsigned short* p) {
    union { unsigned long long q[2]; bf16x8 v; } u;
    u.q[0] = *(const unsigned long long*)(p);
    u.q[1] = *(const unsigned long long*)(p + 4);
    return u.v;
}
__global__ __launch_bounds__(256, 2) void bank_fallback(
    const float* __restrict__ x,
    const float* __restrict__ pW1, const float* __restrict__ pb1,
    const float* __restrict__ pW2, const float* __restrict__ pb2,
    const float* __restrict__ nW1, const float* __restrict__ nb1,
    const float* __restrict__ nW2, const float* __restrict__ nb2,
    float* __restrict__ out)
{
    __shared__ unsigned short Xs [128][XS_LD];
    __shared__ unsigned short W1T[HID][W1_LD];
    __shared__ unsigned short Hs [128][HS_LD];
    __shared__ unsigned short W2T[EMB][W2_LD];
    int p = blockIdx.x;
    int xcd = p & 7, rank = p >> 3;
    int c = xcd * 16 + (rank & 15);
    int btile = (rank >> 4) & 7;
    int bank = rank >> 7;
    int bbase = btile * 128;
    const float* W1c = (bank ? nW1 : pW1) + (size_t)c * IN_DIM * HID;
    const float* b1c = (bank ? nb1 : pb1) + c * HID;
    const float* W2c = (bank ? nW2 : pW2) + (size_t)c * HID * EMB;
    const float* b2c = (bank ? nb2 : pb2) + c * EMB;
    float* outb = out + (size_t)bank * B_TOT * EMB * C_DIM;
    int t = threadIdx.x, wave = t >> 6, lane = t & 63;
    int lr = lane & 15, lkg = lane >> 4, wm = wave >> 1, wn = wave & 1;
    {
        int e0 = (t & 7) * 4, h0 = (t >> 3) * 4;
        f32x4 L0 = *(const f32x4*)&W2c[(h0 + 0) * EMB + e0];
        f32x4 L1 = *(const f32x4*)&W2c[(h0 + 1) * EMB + e0];
        f32x4 L2 = *(const f32x4*)&W2c[(h0 + 2) * EMB + e0];
        f32x4 L3 = *(const f32x4*)&W2c[(h0 + 3) * EMB + e0];
#pragma unroll
        for (int j = 0; j < 4; ++j)
            *(unsigned long long*)&W2T[e0 + j][h0] = pack4(L0[j], L1[j], L2[j], L3[j]);
    }
    float b1v[4];
#pragma unroll
    for (int ni = 0; ni < 4; ++ni) b1v[ni] = b1c[wn * 64 + ni * 16 + lr];
    float b2v[2];
#pragma unroll
    for (int ei = 0; ei < 2; ++ei) b2v[ei] = b2c[ei * 16 + lr];
    f32x4 acc[4][4];
#pragma unroll
    for (int mi = 0; mi < 4; ++mi)
#pragma unroll
        for (int ni = 0; ni < 4; ++ni) acc[mi][ni] = (f32x4){0.f, 0.f, 0.f, 0.f};
    for (int kt = 0; kt < 8; ++kt) {
        int kb = kt * 64;
#pragma unroll
        for (int w8 = 0; w8 < 8; ++w8) {
            int f = w8 * 256 + t;
            int row = f >> 4, col = (f & 15) * 4;
            f32x4 v = *(const f32x4*)&x[(size_t)(bbase + row) * IN_DIM + kb + col];
            *(unsigned long long*)&Xs[row][col] = pack4(v[0], v[1], v[2], v[3]);
        }
#pragma unroll
        for (int g = 0; g < 2; ++g) {
            int s = g * 256 + t;
            int k0 = (s >> 5) * 4, h0 = (s & 31) * 4;
            const float* src = &W1c[(size_t)(kb + k0) * HID + h0];
            f32x4 L0 = *(const f32x4*)(src + 0 * HID);
            f32x4 L1 = *(const f32x4*)(src + 1 * HID);
            f32x4 L2 = *(const f32x4*)(src + 2 * HID);
            f32x4 L3 = *(const f32x4*)(src + 3 * HID);
#pragma unroll
            for (int j = 0; j < 4; ++j)
                *(unsigned long long*)&W1T[h0 + j][k0] = pack4(L0[j], L1[j], L2[j], L3[j]);
        }
        __syncthreads();
#pragma unroll
        for (int ki = 0; ki < 2; ++ki) {
            int kcol = ki * 32 + lkg * 8;
            bf16x8 af[4], bfr[4];
#pragma unroll
            for (int mi = 0; mi < 4; ++mi) af[mi] = load8u(&Xs[wm * 64 + mi * 16 + lr][kcol]);
#pragma unroll
            for (int ni = 0; ni < 4; ++ni) bfr[ni] = load8u(&W1T[wn * 64 + ni * 16 + lr][kcol]);
#pragma unroll
            for (int mi = 0; mi < 4; ++mi)
#pragma unroll
                for (int ni = 0; ni < 4; ++ni)
                    acc[mi][ni] = __builtin_amdgcn_mfma_f32_16x16x32_bf16(
                        af[mi], bfr[ni], acc[mi][ni], 0, 0, 0);
        }
        __syncthreads();
    }
#pragma unroll
    for (int mi = 0; mi < 4; ++mi) {
        int row = wm * 64 + mi * 16 + lkg * 4;
#pragma unroll
        for (int ni = 0; ni < 4; ++ni) {
            int col = wn * 64 + ni * 16 + lr;
#pragma unroll
            for (int j = 0; j < 4; ++j)
                Hs[row + j][col] = f2b(fmaxf(acc[mi][ni][j] + b1v[ni], 0.f));
        }
    }
    __syncthreads();
    f32x4 acc2[2][2];
#pragma unroll
    for (int m2 = 0; m2 < 2; ++m2)
#pragma unroll
        for (int ei = 0; ei < 2; ++ei) acc2[m2][ei] = (f32x4){0.f, 0.f, 0.f, 0.f};
    int rb = wave * 32;
#pragma unroll
    for (int k2 = 0; k2 < 4; ++k2) {
        int kcol = k2 * 32 + lkg * 8;
        bf16x8 a2[2], b2f[2];
#pragma unroll
        for (int m2 = 0; m2 < 2; ++m2) a2[m2] = load8u(&Hs[rb + m2 * 16 + lr][kcol]);
#pragma unroll
        for (int ei = 0; ei < 2; ++ei) b2f[ei] = load8u(&W2T[ei * 16 + lr][kcol]);
#pragma unroll
        for (int m2 = 0; m2 < 2; ++m2)
#pragma unroll
            for (int ei = 0; ei < 2; ++ei)
                acc2[m2][ei] = __builtin_amdgcn_mfma_f32_16x16x32_bf16(
                    a2[m2], b2f[ei], acc2[m2][ei], 0, 0, 0);
    }
#pragma unroll
    for (int m2 = 0; m2 < 2; ++m2)
#pragma unroll
        for (int ei = 0; ei < 2; ++ei) {
            int e = ei * 16 + lr;
#pragma unroll
            for (int j = 0; j < 4; ++j) {
                int brow = bbase + rb + m2 * 16 + lkg * 4 + j;
                outb[((size_t)brow * EMB + e) * C_DIM + c] = acc2[m2][ei][j] + b2v[ei];
            }
        }
}

extern "C" void kernel_launch(void* const* d_in, const int* in_sizes, int n_in,
                              void* d_out, int out_size, void* d_ws, size_t ws_size,
                              hipStream_t stream) {
    const float* x   = (const float*)d_in[0];
    const float* pW1 = (const float*)d_in[1];
    const float* pb1 = (const float*)d_in[2];
    const float* pW2 = (const float*)d_in[3];
    const float* pb2 = (const float*)d_in[4];
    const float* nW1 = (const float*)d_in[5];
    const float* nb1 = (const float*)d_in[6];
    const float* nW2 = (const float*)d_in[7];
    const float* nb2 = (const float*)d_in[8];
    float* out = (float*)d_out;

    if (ws_size >= WS_NEEDED_B) {
        unsigned short* ws = (unsigned short*)d_ws;
        prepass<<<dim3(1024), dim3(256), 0, stream>>>(x, pW1, pW2, nW1, nW2, ws);
        bank_main<<<dim3(2048), dim3(256), 0, stream>>>(pb1, pb2, nb1, nb2, ws, out);
    } else {
        bank_fallback<<<dim3(2048), dim3(256), 0, stream>>>(
            x, pW1, pb1, pW2, pb2, nW1, nb1, nW2, nb2, out);
    }
}

// Round 7
// 90.446 us; speedup vs baseline: 1.6976x; 1.0331x over previous
//
#include <hip/hip_runtime.h>
#include <hip/hip_bf16.h>

#define B_TOT  1024
#define IN_DIM 512
#define C_DIM  128
#define HID    128
#define EMB    32
#define BK     32
#define NKT    (IN_DIM / BK)   // 16

// workspace layout (ushort indices)
#define WS_W1_STRIDE 65536ull                  // per (bank,c): 16 chunks x 4096
#define WS_W2_OFF    16777216ull               // 256 pairs x 4096
#define WS_X_OFF     17825792ull               // [1024][512]
#define WS_NEEDED_B  36700160ull               // bytes

using bf16x8 = __attribute__((ext_vector_type(8))) short;
using f32x4  = __attribute__((ext_vector_type(4))) float;

__device__ __forceinline__ unsigned short f2b(float f) {
    union { __hip_bfloat16 h; unsigned short u; } cv;
    cv.h = __float2bfloat16(f);
    return cv.u;
}
__device__ __forceinline__ unsigned int pack2(float a, float b) {
    return (unsigned int)f2b(a) | ((unsigned int)f2b(b) << 16);
}
__device__ __forceinline__ unsigned long long pack4(float a, float b, float c, float d) {
    return (unsigned long long)pack2(a, b) | ((unsigned long long)pack2(c, d) << 32);
}
__device__ __forceinline__ bf16x8 ld16(const unsigned short* p) {
    return *(const bf16x8*)p;
}
__device__ __forceinline__ void g2l16(const unsigned short* g, unsigned short* l) {
    __builtin_amdgcn_global_load_lds(
        (const __attribute__((address_space(1))) unsigned int*)(g),
        (__attribute__((address_space(3))) unsigned int*)(l), 16, 0, 0);
}

// Swizzles (involutions, pre-applied in ws so g2l stays linear):
//  32-wide rows (X tiles, W1 chunks): elem (r,k): r*32 + ((((r>>1)&3) ^ (k>>3 & 3))<<3) + (k&7)
//  128-wide rows (Hs):               elem (r,h): r*128 + (((h>>3) ^ (r&7))<<3) + (h&7)

// ============================ prepass ============================
__global__ __launch_bounds__(256) void prepass(
    const float* __restrict__ x,
    const float* __restrict__ pW1, const float* __restrict__ pW2,
    const float* __restrict__ nW1, const float* __restrict__ nW2,
    unsigned short* __restrict__ ws)
{
    __shared__ unsigned short img[4096];   // 8 KB
    const int blk     = blockIdx.x;
    const int pair    = blk >> 2;          // bank*128 + c
    const int quarter = blk & 3;
    const int bank    = pair >> 7;
    const int c       = pair & 127;
    const int t       = threadIdx.x;

    const float* W1c = (bank ? nW1 : pW1) + (size_t)c * IN_DIM * HID;
    const float* W2c = (bank ? nW2 : pW2) + (size_t)c * HID * EMB;

    // ---- W2 (quarter 0 only): transpose -> [e][h] flat, bf16 ----
    if (quarter == 0) {
        int e0 = (t & 7) * 4, h0 = (t >> 3) * 4;
        const float* src = &W2c[(size_t)h0 * EMB + e0];
        f32x4 L0 = *(const f32x4*)(src + 0 * EMB);
        f32x4 L1 = *(const f32x4*)(src + 1 * EMB);
        f32x4 L2 = *(const f32x4*)(src + 2 * EMB);
        f32x4 L3 = *(const f32x4*)(src + 3 * EMB);
        unsigned short* dst = ws + WS_W2_OFF + (size_t)pair * 4096;
#pragma unroll
        for (int j = 0; j < 4; ++j)
            *(unsigned long long*)&dst[(e0 + j) * 128 + h0] =
                pack4(L0[j], L1[j], L2[j], L3[j]);
    }

    // ---- W1: four 32-k chunks per block, transposed + swizzled ----
#pragma unroll
    for (int q = 0; q < 4; ++q) {
        const int kt = quarter * 4 + q;
        const float* Wk = W1c + (size_t)kt * BK * HID;
        {
            int k0 = (t >> 5) * 4;       // 0..28
            int h0 = (t & 31) * 4;       // 0..124
            const float* src = &Wk[(size_t)k0 * HID + h0];
            f32x4 L0 = *(const f32x4*)(src + 0 * HID);
            f32x4 L1 = *(const f32x4*)(src + 1 * HID);
            f32x4 L2 = *(const f32x4*)(src + 2 * HID);
            f32x4 L3 = *(const f32x4*)(src + 3 * HID);
#pragma unroll
            for (int j = 0; j < 4; ++j) {
                int h = h0 + j;
                int slot = ((h >> 1) & 3) ^ (k0 >> 3);
                *(unsigned long long*)&img[h * 32 + (slot << 3) + (k0 & 7)] =
                    pack4(L0[j], L1[j], L2[j], L3[j]);
            }
        }
        __syncthreads();
        unsigned short* dst = ws + (size_t)pair * WS_W1_STRIDE + (size_t)kt * 4096;
        *(bf16x8*)&dst[t * 16]     = *(const bf16x8*)&img[t * 16];
        *(bf16x8*)&dst[t * 16 + 8] = *(const bf16x8*)&img[t * 16 + 8];
        __syncthreads();
    }

    // ---- x: one row per block, swizzle pre-applied within 32-k chunks ----
    {
        const int row = blk;              // 0..1023
        if (t < 128) {
            int k0  = t * 4;
            int cb  = k0 & ~31;
            int kg  = (k0 >> 3) & 3;
            int ks  = cb + (((kg ^ ((row >> 1) & 3))) << 3) + (k0 & 7);
            f32x4 v = *(const f32x4*)&x[(size_t)row * IN_DIM + ks];
            *(unsigned long long*)&ws[WS_X_OFF + (size_t)row * IN_DIM + k0] =
                pack4(v[0], v[1], v[2], v[3]);
        }
    }
}

// ============================ main ============================
// 2048 blocks, 256 thr, 48 KB static LDS -> 3 blocks/CU (12 waves/CU).
// Counted-vmcnt software pipeline: stage tile kt+2 at step kt; never drain.
// smem (ushort idx): X bufs @0/4096/8192, W bufs @12288/16384/20480.
// Hs overlays [0,16384) after the K-loop.
__global__ __launch_bounds__(256, 3) void bank_main(
    const float* __restrict__ pb1, const float* __restrict__ pb2,
    const float* __restrict__ nb1, const float* __restrict__ nb2,
    const unsigned short* __restrict__ ws,
    float* __restrict__ out)
{
    __shared__ unsigned short smem[24576];   // 48 KB

    const int p     = blockIdx.x;
    const int xcd   = p & 7;
    const int rank  = p >> 3;             // 0..255
    const int c     = xcd * 16 + (rank & 15);
    const int btile = (rank >> 4) & 7;
    const int bank  = rank >> 7;
    const int pair  = bank * 128 + c;
    const int bbase = btile * 128;

    const int t    = threadIdx.x;
    const int wave = t >> 6;
    const int lane = t & 63;
    const int lr   = lane & 15;
    const int lkg  = lane >> 4;   // k-group 0..3 (K=32)
    const int wm   = wave >> 1;
    const int wn   = wave & 1;

    const unsigned short* w1base = ws + (size_t)pair * WS_W1_STRIDE;
    const unsigned short* xbase  = ws + WS_X_OFF + (size_t)bbase * IN_DIM;

    f32x4 acc[4][4];
#pragma unroll
    for (int mi = 0; mi < 4; ++mi)
#pragma unroll
        for (int ni = 0; ni < 4; ++ni) acc[mi][ni] = (f32x4){0.f, 0.f, 0.f, 0.f};

    // stage one 8 KB tile = 2 g2l16 per thread (4 vmem per thread per tile pair)
#define STAGE_X(kt, sel)                                                        \
    {                                                                           \
        _Pragma("unroll")                                                       \
        for (int i = 0; i < 2; ++i) {                                           \
            int inst = wave * 2 + i;                                            \
            int row  = inst * 16 + (lane >> 2);                                 \
            g2l16(&xbase[(size_t)row * IN_DIM + (kt) * BK + (lane & 3) * 8],    \
                  &smem[(sel) * 4096 + inst * 512]);                            \
        }                                                                       \
    }
#define STAGE_W(kt, sel)                                                        \
    {                                                                           \
        const unsigned short* src = w1base + (size_t)(kt) * 4096;               \
        _Pragma("unroll")                                                       \
        for (int i = 0; i < 2; ++i) {                                           \
            int inst = wave * 2 + i;                                            \
            g2l16(&src[inst * 512 + lane * 8],                                  \
                  &smem[12288 + (sel) * 4096 + inst * 512]);                    \
        }                                                                       \
    }

// One pipelined K-step. Barriers are RAW (no vmcnt drain); VM = counted wait.
// bar1: tile KT landed in LDS (vmcnt(VM) first). bar2: all waves' ds_reads of
// tile KT complete (lgkmcnt(0) first) -> safe for stage(KT+2) to overwrite
// the buffer read at step KT-1 (two barriers back). sched_barrier(0) pins
// ordering around the asm waits (rule 18).
#define STEP(KT, VM, DOSTAGE)                                                   \
    {                                                                           \
        asm volatile("s_waitcnt vmcnt(" #VM ")" ::: "memory");                  \
        __builtin_amdgcn_s_barrier();                                           \
        __builtin_amdgcn_sched_barrier(0);                                      \
        const unsigned short* Xb = &smem[((KT) % 3) * 4096];                    \
        const unsigned short* Wb = &smem[12288 + ((KT) % 3) * 4096];            \
        bf16x8 af[4], bfr[4];                                                   \
        _Pragma("unroll")                                                       \
        for (int mi = 0; mi < 4; ++mi) {                                        \
            int r = wm * 64 + mi * 16 + lr;                                     \
            int slot = ((r >> 1) & 3) ^ lkg;                                    \
            af[mi] = ld16(&Xb[r * 32 + (slot << 3)]);                           \
        }                                                                       \
        _Pragma("unroll")                                                       \
        for (int ni = 0; ni < 4; ++ni) {                                        \
            int h = wn * 64 + ni * 16 + lr;                                     \
            int slot = ((h >> 1) & 3) ^ lkg;                                    \
            bfr[ni] = ld16(&Wb[h * 32 + (slot << 3)]);                          \
        }                                                                       \
        asm volatile("s_waitcnt lgkmcnt(0)" ::: "memory");                      \
        __builtin_amdgcn_sched_barrier(0);                                      \
        __builtin_amdgcn_s_barrier();                                           \
        __builtin_amdgcn_sched_barrier(0);                                      \
        if (DOSTAGE) {                                                          \
            STAGE_X((KT) + 2, ((KT) + 2) % 3);                                  \
            STAGE_W((KT) + 2, ((KT) + 2) % 3);                                  \
        }                                                                       \
        __builtin_amdgcn_s_setprio(1);                                          \
        _Pragma("unroll")                                                       \
        for (int mi = 0; mi < 4; ++mi)                                          \
            _Pragma("unroll")                                                   \
            for (int ni = 0; ni < 4; ++ni)                                      \
                acc[mi][ni] = __builtin_amdgcn_mfma_f32_16x16x32_bf16(          \
                    af[mi], bfr[ni], acc[mi][ni], 0, 0, 0);                     \
        __builtin_amdgcn_s_setprio(0);                                          \
    }

    // prologue: tiles 0 and 1 in flight (8 vmem outstanding)
    STAGE_X(0, 0); STAGE_W(0, 0);
    STAGE_X(1, 1); STAGE_W(1, 1);

    STEP(0, 4, 1)  STEP(1, 4, 1)  STEP(2, 4, 1)  STEP(3, 4, 1)
    STEP(4, 4, 1)  STEP(5, 4, 1)  STEP(6, 4, 1)  STEP(7, 4, 1)
    STEP(8, 4, 1)  STEP(9, 4, 1)  STEP(10, 4, 1) STEP(11, 4, 1)
    STEP(12, 4, 1) STEP(13, 4, 1) STEP(14, 4, 0) STEP(15, 0, 0)

    __syncthreads();   // all waves done with K-loop buffers before Hs overlay

    // biases loaded only now (keeps K-loop register pressure low)
    const float* b1c = (bank ? nb1 : pb1) + c * HID;
    const float* b2c = (bank ? nb2 : pb2) + c * EMB;
    float b1v[4];
#pragma unroll
    for (int ni = 0; ni < 4; ++ni) b1v[ni] = b1c[wn * 64 + ni * 16 + lr];

    // epilogue1: bias+relu -> Hs (swizzled [r][h]) over smem[0..16384)
#pragma unroll
    for (int mi = 0; mi < 4; ++mi) {
        int row0 = wm * 64 + mi * 16 + lkg * 4;
#pragma unroll
        for (int ni = 0; ni < 4; ++ni) {
            int col = wn * 64 + ni * 16 + lr;
            int kgH = col >> 3, kin = col & 7;
#pragma unroll
            for (int j = 0; j < 4; ++j) {
                int r = row0 + j;
                float v = fmaxf(acc[mi][ni][j] + b1v[ni], 0.f);
                smem[r * 128 + ((kgH ^ (r & 7)) << 3) + kin] = f2b(v);
            }
        }
    }
    __syncthreads();

    // W2 fragments from ws (bf16 [e][h])
    const unsigned short* w2base = ws + WS_W2_OFF + (size_t)pair * 4096;
    bf16x8 w2f[2][4];
#pragma unroll
    for (int ei = 0; ei < 2; ++ei)
#pragma unroll
        for (int k2 = 0; k2 < 4; ++k2)
            w2f[ei][k2] = ld16(&w2base[(ei * 16 + lr) * 128 + (k2 * 4 + lkg) * 8]);
    float b2v[2];
#pragma unroll
    for (int ei = 0; ei < 2; ++ei) b2v[ei] = b2c[ei * 16 + lr];

    // GEMM2: M=128, N=32, K=128; each wave 32 rows
    f32x4 acc2[2][2];
#pragma unroll
    for (int m2 = 0; m2 < 2; ++m2)
#pragma unroll
        for (int ei = 0; ei < 2; ++ei) acc2[m2][ei] = (f32x4){0.f, 0.f, 0.f, 0.f};
    const int rb = wave * 32;
#pragma unroll
    for (int k2 = 0; k2 < 4; ++k2) {
        int kg = k2 * 4 + lkg;
        bf16x8 a2[2];
#pragma unroll
        for (int m2 = 0; m2 < 2; ++m2) {
            int r = rb + m2 * 16 + lr;
            a2[m2] = ld16(&smem[r * 128 + ((kg ^ (r & 7)) << 3)]);
        }
#pragma unroll
        for (int m2 = 0; m2 < 2; ++m2)
#pragma unroll
            for (int ei = 0; ei < 2; ++ei)
                acc2[m2][ei] = __builtin_amdgcn_mfma_f32_16x16x32_bf16(
                    a2[m2], w2f[ei][k2], acc2[m2][ei], 0, 0, 0);
    }

    float* outb = out + (size_t)bank * B_TOT * EMB * C_DIM;
#pragma unroll
    for (int m2 = 0; m2 < 2; ++m2) {
#pragma unroll
        for (int ei = 0; ei < 2; ++ei) {
            int e = ei * 16 + lr;
#pragma unroll
            for (int j = 0; j < 4; ++j) {
                int brow = bbase + rb + m2 * 16 + lkg * 4 + j;
                outb[((size_t)brow * EMB + e) * C_DIM + c] = acc2[m2][ei][j] + b2v[ei];
            }
        }
    }
#undef STEP
#undef STAGE_X
#undef STAGE_W
}

// ===================== fallback (round-1 kernel, known-good) =====================
#define XS_LD 68
#define W1_LD 68
#define HS_LD 132
#define W2_LD 132
__device__ __forceinline__ bf16x8 load8u(const unsigned short* p) {
    union { unsigned long long q[2]; bf16x8 v; } u;
    u.q[0] = *(const unsigned long long*)(p);
    u.q[1] = *(const unsigned long long*)(p + 4);
    return u.v;
}
__global__ __launch_bounds__(256, 2) void bank_fallback(
    const float* __restrict__ x,
    const float* __restrict__ pW1, const float* __restrict__ pb1,
    const float* __restrict__ pW2, const float* __restrict__ pb2,
    const float* __restrict__ nW1, const float* __restrict__ nb1,
    const float* __restrict__ nW2, const float* __restrict__ nb2,
    float* __restrict__ out)
{
    __shared__ unsigned short Xs [128][XS_LD];
    __shared__ unsigned short W1T[HID][W1_LD];
    __shared__ unsigned short Hs [128][HS_LD];
    __shared__ unsigned short W2T[EMB][W2_LD];
    int p = blockIdx.x;
    int xcd = p & 7, rank = p >> 3;
    int c = xcd * 16 + (rank & 15);
    int btile = (rank >> 4) & 7;
    int bank = rank >> 7;
    int bbase = btile * 128;
    const float* W1c = (bank ? nW1 : pW1) + (size_t)c * IN_DIM * HID;
    const float* b1c = (bank ? nb1 : pb1) + c * HID;
    const float* W2c = (bank ? nW2 : pW2) + (size_t)c * HID * EMB;
    const float* b2c = (bank ? nb2 : pb2) + c * EMB;
    float* outb = out + (size_t)bank * B_TOT * EMB * C_DIM;
    int t = threadIdx.x, wave = t >> 6, lane = t & 63;
    int lr = lane & 15, lkg = lane >> 4, wm = wave >> 1, wn = wave & 1;
    {
        int e0 = (t & 7) * 4, h0 = (t >> 3) * 4;
        f32x4 L0 = *(const f32x4*)&W2c[(h0 + 0) * EMB + e0];
        f32x4 L1 = *(const f32x4*)&W2c[(h0 + 1) * EMB + e0];
        f32x4 L2 = *(const f32x4*)&W2c[(h0 + 2) * EMB + e0];
        f32x4 L3 = *(const f32x4*)&W2c[(h0 + 3) * EMB + e0];
#pragma unroll
        for (int j = 0; j < 4; ++j)
            *(unsigned long long*)&W2T[e0 + j][h0] = pack4(L0[j], L1[j], L2[j], L3[j]);
    }
    float b1v[4];
#pragma unroll
    for (int ni = 0; ni < 4; ++ni) b1v[ni] = b1c[wn * 64 + ni * 16 + lr];
    float b2v[2];
#pragma unroll
    for (int ei = 0; ei < 2; ++ei) b2v[ei] = b2c[ei * 16 + lr];
    f32x4 acc[4][4];
#pragma unroll
    for (int mi = 0; mi < 4; ++mi)
#pragma unroll
        for (int ni = 0; ni < 4; ++ni) acc[mi][ni] = (f32x4){0.f, 0.f, 0.f, 0.f};
    for (int kt = 0; kt < 8; ++kt) {
        int kb = kt * 64;
#pragma unroll
        for (int w8 = 0; w8 < 8; ++w8) {
            int f = w8 * 256 + t;
            int row = f >> 4, col = (f & 15) * 4;
            f32x4 v = *(const f32x4*)&x[(size_t)(bbase + row) * IN_DIM + kb + col];
            *(unsigned long long*)&Xs[row][col] = pack4(v[0], v[1], v[2], v[3]);
        }
#pragma unroll
        for (int g = 0; g < 2; ++g) {
            int s = g * 256 + t;
            int k0 = (s >> 5) * 4, h0 = (s & 31) * 4;
            const float* src = &W1c[(size_t)(kb + k0) * HID + h0];
            f32x4 L0 = *(const f32x4*)(src + 0 * HID);
            f32x4 L1 = *(const f32x4*)(src + 1 * HID);
            f32x4 L2 = *(const f32x4*)(src + 2 * HID);
            f32x4 L3 = *(const f32x4*)(src + 3 * HID);
#pragma unroll
            for (int j = 0; j < 4; ++j)
                *(unsigned long long*)&W1T[h0 + j][k0] = pack4(L0[j], L1[j], L2[j], L3[j]);
        }
        __syncthreads();
#pragma unroll
        for (int ki = 0; ki < 2; ++ki) {
            int kcol = ki * 32 + lkg * 8;
            bf16x8 af[4], bfr[4];
#pragma unroll
            for (int mi = 0; mi < 4; ++mi) af[mi] = load8u(&Xs[wm * 64 + mi * 16 + lr][kcol]);
#pragma unroll
            for (int ni = 0; ni < 4; ++ni) bfr[ni] = load8u(&W1T[wn * 64 + ni * 16 + lr][kcol]);
#pragma unroll
            for (int mi = 0; mi < 4; ++mi)
#pragma unroll
                for (int ni = 0; ni < 4; ++ni)
                    acc[mi][ni] = __builtin_amdgcn_mfma_f32_16x16x32_bf16(
                        af[mi], bfr[ni], acc[mi][ni], 0, 0, 0);
        }
        __syncthreads();
    }
#pragma unroll
    for (int mi = 0; mi < 4; ++mi) {
        int row = wm * 64 + mi * 16 + lkg * 4;
#pragma unroll
        for (int ni = 0; ni < 4; ++ni) {
            int col = wn * 64 + ni * 16 + lr;
#pragma unroll
            for (int j = 0; j < 4; ++j)
                Hs[row + j][col] = f2b(fmaxf(acc[mi][ni][j] + b1v[ni], 0.f));
        }
    }
    __syncthreads();
    f32x4 acc2[2][2];
#pragma unroll
    for (int m2 = 0; m2 < 2; ++m2)
#pragma unroll
        for (int ei = 0; ei < 2; ++ei) acc2[m2][ei] = (f32x4){0.f, 0.f, 0.f, 0.f};
    int rb = wave * 32;
#pragma unroll
    for (int k2 = 0; k2 < 4; ++k2) {
        int kcol = k2 * 32 + lkg * 8;
        bf16x8 a2[2], b2f[2];
#pragma unroll
        for (int m2 = 0; m2 < 2; ++m2) a2[m2] = load8u(&Hs[rb + m2 * 16 + lr][kcol]);
#pragma unroll
        for (int ei = 0; ei < 2; ++ei) b2f[ei] = load8u(&W2T[ei * 16 + lr][kcol]);
#pragma unroll
        for (int m2 = 0; m2 < 2; ++m2)
#pragma unroll
            for (int ei = 0; ei < 2; ++ei)
                acc2[m2][ei] = __builtin_amdgcn_mfma_f32_16x16x32_bf16(
                    a2[m2], b2f[ei], acc2[m2][ei], 0, 0, 0);
    }
#pragma unroll
    for (int m2 = 0; m2 < 2; ++m2)
#pragma unroll
        for (int ei = 0; ei < 2; ++ei) {
            int e = ei * 16 + lr;
#pragma unroll
            for (int j = 0; j < 4; ++j) {
                int brow = bbase + rb + m2 * 16 + lkg * 4 + j;
                outb[((size_t)brow * EMB + e) * C_DIM + c] = acc2[m2][ei][j] + b2v[ei];
            }
        }
}

extern "C" void kernel_launch(void* const* d_in, const int* in_sizes, int n_in,
                              void* d_out, int out_size, void* d_ws, size_t ws_size,
                              hipStream_t stream) {
    const float* x   = (const float*)d_in[0];
    const float* pW1 = (const float*)d_in[1];
    const float* pb1 = (const float*)d_in[2];
    const float* pW2 = (const float*)d_in[3];
    const float* pb2 = (const float*)d_in[4];
    const float* nW1 = (const float*)d_in[5];
    const float* nb1 = (const float*)d_in[6];
    const float* nW2 = (const float*)d_in[7];
    const float* nb2 = (const float*)d_in[8];
    float* out = (float*)d_out;

    if (ws_size >= WS_NEEDED_B) {
        unsigned short* ws = (unsigned short*)d_ws;
        prepass<<<dim3(1024), dim3(256), 0, stream>>>(x, pW1, pW2, nW1, nW2, ws);
        bank_main<<<dim3(2048), dim3(256), 0, stream>>>(pb1, pb2, nb1, nb2, ws, out);
    } else {
        bank_fallback<<<dim3(2048), dim3(256), 0, stream>>>(
            x, pW1, pb1, pW2, pb2, nW1, nb1, nW2, nb2, out);
    }
}